// Round 4
// baseline (236.052 us; speedup 1.0000x reference)
//
#include <hip/hip_runtime.h>

// RNN: h_{t+1} = relu(x_t*W_ih^T + b_ih + b_hh + W_hh·h_t), out = fc(h_T).
// B=4096, T=1000, H=20.
//
// R19b: 8 lanes/batch (was 16). Evidence: harness time tracks instruction
// count (R17: +3 instr/step -> harness +4% despite rocprof -40%), i.e.
// power/energy-bound in sustained mode. Cut VALU instr/batch-step 8.5->5.5:
//   lane (a,kh): rows 5a..5a+4  x  k-half 10kh..10kh+9   (every step, no
//   even/odd role alternation).
//   - fold: ONE quad_perm xor1 round (partner = other k-half), 5 DPP adds
//   - relu/init/merge amortize over 8 batches/wave instead of 4
//   - h redistribution (own 5-row slice -> needed 10-k half) via 10
//     ds_bpermute with STATIC per-lane addresses (slice replication makes
//     the permutation fixed): slice A from lane (base|4kh), B from +2 lanes.
// 512 waves (half the SIMDs active): wall = per-wave time, idle SIMDs save
// power. X/Y chain split retained (R17): X=init+k0..k4, Y=k5..k9, pk merge.

#define TT 1000

typedef float v2f __attribute__((ext_vector_type(2)));

// one column k of a 5-row x 10-col tile: rows packed (r0,r1),(r2,r3),r4
struct Col { v2f p01, p23; float v4; };

// precomputed input projection x*W_ih + (b_ih+b_hh), masked to kh==0 lanes
struct Init { v2f i01, i23; float i4; };

#define PIN(v)  asm volatile("" : "+v"(v))
__device__ __forceinline__ void pinc(Col& c) {
    PIN(c.p01); PIN(c.p23); PIN(c.v4);
}
__device__ __forceinline__ void keepc(const Col& c) {
    asm volatile("" :: "v"(c.p01), "v"(c.p23), "v"(c.v4));
}

__device__ __forceinline__ float dpp_xor1(float v) {
    // quad_perm [1,0,3,2]: lane <-> lane^1 (the other k-half). old=0 +
    // bound_ctrl + full masks -> GCNDPPCombine fuses into v_add_f32_dpp.
    return __int_as_float(__builtin_amdgcn_update_dpp(
        0, __float_as_int(v), 0xB1, 0xF, 0xF, true));
}

__device__ __forceinline__ float bpf(int addr, float v) {
    return __int_as_float(__builtin_amdgcn_ds_bpermute(addr, __float_as_int(v)));
}

__device__ __forceinline__ Init mkinit(float xt, const Col& w, const Col& b) {
    const v2f xs = {xt, xt};
    Init r;
    r.i01 = __builtin_elementwise_fma(xs, w.p01, b.p01);
    r.i23 = __builtin_elementwise_fma(xs, w.p23, b.p23);
    r.i4  = __builtin_fmaf(xt, w.v4, b.v4);
    return r;
}

// One timestep (uniform roles). Consumes hA (k 0..4) / hB (k 5..9),
// produces own-slice h01/h23/h4 and the NEXT step's hA/hB via bpermute.
__device__ __forceinline__ void step(const Init& in,
    v2f& h01, v2f& h23, float& h4,
    v2f& hA01, v2f& hA23, float& hA4,
    v2f& hB01, v2f& hB23, float& hB4,
    int addrA, int addrB,
    const Col& c0, const Col& c1, const Col& c2, const Col& c3, const Col& c4,
    const Col& c5, const Col& c6, const Col& c7, const Col& c8, const Col& c9)
{
    // --- chain X: init + k0..k4 (A-slice)
    v2f  X01 = __builtin_elementwise_fma(hA01.xx, c0.p01, in.i01);
    v2f  X23 = __builtin_elementwise_fma(hA01.xx, c0.p23, in.i23);
    float x4 = __builtin_fmaf(hA01.x, c0.v4, in.i4);
    X01 = __builtin_elementwise_fma(hA01.yy, c1.p01, X01);
    X23 = __builtin_elementwise_fma(hA01.yy, c1.p23, X23);
    x4  = __builtin_fmaf(hA01.y, c1.v4, x4);
    X01 = __builtin_elementwise_fma(hA23.xx, c2.p01, X01);
    X23 = __builtin_elementwise_fma(hA23.xx, c2.p23, X23);
    x4  = __builtin_fmaf(hA23.x, c2.v4, x4);
    X01 = __builtin_elementwise_fma(hA23.yy, c3.p01, X01);
    X23 = __builtin_elementwise_fma(hA23.yy, c3.p23, X23);
    x4  = __builtin_fmaf(hA23.y, c3.v4, x4);
    { const v2f s = {hA4, hA4};
      X01 = __builtin_elementwise_fma(s, c4.p01, X01);
      X23 = __builtin_elementwise_fma(s, c4.p23, X23);
      x4  = __builtin_fmaf(hA4, c4.v4, x4); }

    // --- chain Y: k5..k9 (B-slice)
    v2f  Y01 = hB01.xx * c5.p01;
    v2f  Y23 = hB01.xx * c5.p23;
    float y4 = hB01.x * c5.v4;
    Y01 = __builtin_elementwise_fma(hB01.yy, c6.p01, Y01);
    Y23 = __builtin_elementwise_fma(hB01.yy, c6.p23, Y23);
    y4  = __builtin_fmaf(hB01.y, c6.v4, y4);
    Y01 = __builtin_elementwise_fma(hB23.xx, c7.p01, Y01);
    Y23 = __builtin_elementwise_fma(hB23.xx, c7.p23, Y23);
    y4  = __builtin_fmaf(hB23.x, c7.v4, y4);
    Y01 = __builtin_elementwise_fma(hB23.yy, c8.p01, Y01);
    Y23 = __builtin_elementwise_fma(hB23.yy, c8.p23, Y23);
    y4  = __builtin_fmaf(hB23.y, c8.v4, y4);
    { const v2f s = {hB4, hB4};
      Y01 = __builtin_elementwise_fma(s, c9.p01, Y01);
      Y23 = __builtin_elementwise_fma(s, c9.p23, Y23);
      y4  = __builtin_fmaf(hB4, c9.v4, y4); }

    const v2f z = {0.f, 0.f};

    // --- per-pair finalize depth-first; bpermutes issue as soon as each
    //     pair's relu is done (earliest consumer next step is hA01).
    {
        v2f A = X01 + Y01;                        // v_pk_add_f32
        float t0 = dpp_xor1(A.x), t1 = dpp_xor1(A.y);
        v2f r = {A.x + t0, A.y + t1};
        h01 = __builtin_elementwise_max(r, z);    // v_pk_max_f32
        hA01 = (v2f){ bpf(addrA, h01.x), bpf(addrA, h01.y) };
        hB01 = (v2f){ bpf(addrB, h01.x), bpf(addrB, h01.y) };
    }
    {
        v2f A = X23 + Y23;
        float t2 = dpp_xor1(A.x), t3 = dpp_xor1(A.y);
        v2f r = {A.x + t2, A.y + t3};
        h23 = __builtin_elementwise_max(r, z);
        hA23 = (v2f){ bpf(addrA, h23.x), bpf(addrA, h23.y) };
        hB23 = (v2f){ bpf(addrB, h23.x), bpf(addrB, h23.y) };
    }
    {
        float b4 = x4 + y4;
        float t4 = dpp_xor1(b4);
        h4 = fmaxf(b4 + t4, 0.f);
        hA4 = bpf(addrA, h4);
        hB4 = bpf(addrB, h4);
    }
}

__global__ void
__attribute__((amdgpu_flat_work_group_size(64, 64), amdgpu_waves_per_eu(1, 1)))
rnn_os_kernel(const float* __restrict__ x,
              const float* __restrict__ W_ih,
              const float* __restrict__ W_hh,
              const float* __restrict__ b_ih,
              const float* __restrict__ b_hh,
              const float* __restrict__ fc_w,
              const float* __restrict__ fc_b,
              float* __restrict__ out) {
    const int tid = blockIdx.x * 64 + threadIdx.x;
    const int b   = tid >> 3;     // batch element (8 lanes per batch)
    const int j   = tid & 7;      // lane in 8-lane group
    const int a   = j >> 1;       // row group: rows 5a..5a+4
    const int kh  = j & 1;        // k half:    k 10kh..10kh+9

    // bpermute source lanes (within-wave lane index, block = 1 wave):
    // slice A (h[10kh..10kh+4])  lives replicated at lanes (a=2kh,  kh'=0)
    // slice B (h[10kh+5..10kh+9]) at lanes (a=2kh+1, kh'=0)
    const int l      = threadIdx.x;            // wave lane
    const int srcA   = (l & ~7) | (kh << 2);   // group base + 4*kh
    const int addrA  = srcA << 2;              // byte address
    const int addrB  = addrA + 8;              // + 2 lanes

    // --- weight tile: rows 5a..5a+4 x cols 10kh..10kh+9, packed rows
    Col c0, c1, c2, c3, c4, c5, c6, c7, c8, c9;
#define LOADC(ck, k)                                                          \
    { const int col = kh * 10 + (k);                                          \
      (ck).p01 = (v2f){ W_hh[(a * 5 + 0) * 20 + col],                         \
                        W_hh[(a * 5 + 1) * 20 + col] };                       \
      (ck).p23 = (v2f){ W_hh[(a * 5 + 2) * 20 + col],                         \
                        W_hh[(a * 5 + 3) * 20 + col] };                       \
      (ck).v4  =        W_hh[(a * 5 + 4) * 20 + col]; }
    LOADC(c0, 0) LOADC(c1, 1) LOADC(c2, 2) LOADC(c3, 3) LOADC(c4, 4)
    LOADC(c5, 5) LOADC(c6, 6) LOADC(c7, 7) LOADC(c8, 8) LOADC(c9, 9)
#undef LOADC

    const bool act = (kh == 0);   // init/bias contributed once per row
    Col wie, bie;
    {
        const float* pw = W_ih + a * 5;
        const float* p1 = b_ih + a * 5;
        const float* p2 = b_hh + a * 5;
        wie.p01 = (v2f){ act ? pw[0] : 0.f, act ? pw[1] : 0.f };
        wie.p23 = (v2f){ act ? pw[2] : 0.f, act ? pw[3] : 0.f };
        wie.v4  =        act ? pw[4] : 0.f;
        bie.p01 = (v2f){ act ? (p1[0] + p2[0]) : 0.f,
                         act ? (p1[1] + p2[1]) : 0.f };
        bie.p23 = (v2f){ act ? (p1[2] + p2[2]) : 0.f,
                         act ? (p1[3] + p2[3]) : 0.f };
        bie.v4  =        act ? (p1[4] + p2[4]) : 0.f;
    }

    pinc(c0); pinc(c1); pinc(c2); pinc(c3); pinc(c4);
    pinc(c5); pinc(c6); pinc(c7); pinc(c8); pinc(c9);
    pinc(wie); pinc(bie);

    v2f h01 = {0.f, 0.f}, h23 = {0.f, 0.f};
    float h4 = 0.f;
    v2f hA01 = {0.f, 0.f}, hA23 = {0.f, 0.f};
    float hA4 = 0.f;
    v2f hB01 = {0.f, 0.f}, hB23 = {0.f, 0.f};
    float hB4 = 0.f;

    const float* __restrict__ xb = x + (size_t)b * TT;

    // --- 20-step register blocks (5 float4 each), double-buffered.
#define LOAD5(P, off)                                   \
    P##0 = *(const float4*)(xb + (off));                \
    P##1 = *(const float4*)(xb + (off) + 4);            \
    P##2 = *(const float4*)(xb + (off) + 8);            \
    P##3 = *(const float4*)(xb + (off) + 12);           \
    P##4 = *(const float4*)(xb + (off) + 16);

#define STEP1(XT) {                                                        \
        const Init in_ = mkinit((XT), wie, bie);                           \
        step(in_, h01, h23, h4, hA01, hA23, hA4, hB01, hB23, hB4,          \
             addrA, addrB, c0, c1, c2, c3, c4, c5, c6, c7, c8, c9); }
#define RUN4(Q) { STEP1(Q.x) STEP1(Q.y) STEP1(Q.z) STEP1(Q.w) }
#define RUN20(P) RUN4(P##0) RUN4(P##1) RUN4(P##2) RUN4(P##3) RUN4(P##4)

    float4 A0, A1, A2, A3, A4;
    float4 B0, B1, B2, B3, B4;
    LOAD5(A, 0)    // block 0: steps 0..19
    LOAD5(B, 20)   // block 1: steps 20..39

    // 24 iterations x 40 steps = 960, then blocks 48,49 as the tail.
    for (int it = 0; it < 24; ++it) {
        const int base = it * 40;
        RUN20(A)                    // steps base .. base+19
        LOAD5(A, base + 40)         // block 2it+2
        RUN20(B)                    // steps base+20 .. base+39
        LOAD5(B, base + 60)         // block 2it+3
    }
    RUN20(A)                        // steps 960..979
    RUN20(B)                        // steps 980..999

#undef RUN20
#undef RUN4
#undef STEP1
#undef LOAD5

    keepc(c0); keepc(c1); keepc(c2); keepc(c3); keepc(c4);
    keepc(c5); keepc(c6); keepc(c7); keepc(c8); keepc(c9);
    keepc(wie); keepc(bie);

    // Final: lane (a,kh) holds h[5a..5a+4] (replicated over kh).
    // Mask fc weights to kh==0, dot, reduce across the 8-lane group.
    float dot;
    {
        const float* pf = fc_w + a * 5;
        float f0 = act ? pf[0] : 0.f, f1 = act ? pf[1] : 0.f;
        float f2 = act ? pf[2] : 0.f, f3 = act ? pf[3] : 0.f;
        float f4 = act ? pf[4] : 0.f;
        dot = h01.x * f0;
        dot = __builtin_fmaf(h01.y, f1, dot);
        dot = __builtin_fmaf(h23.x, f2, dot);
        dot = __builtin_fmaf(h23.y, f3, dot);
        dot = __builtin_fmaf(h4,    f4, dot);
    }
    dot += __shfl_xor(dot, 1, 8);
    dot += __shfl_xor(dot, 2, 8);
    dot += __shfl_xor(dot, 4, 8);

    if (j == 0)
        out[b] = dot + fc_b[0];
}

extern "C" void kernel_launch(void* const* d_in, const int* in_sizes, int n_in,
                              void* d_out, int out_size, void* d_ws, size_t ws_size,
                              hipStream_t stream) {
    const float* x    = (const float*)d_in[0];
    const float* W_ih = (const float*)d_in[1];
    const float* W_hh = (const float*)d_in[2];
    const float* b_ih = (const float*)d_in[3];
    const float* b_hh = (const float*)d_in[4];
    const float* fc_w = (const float*)d_in[5];
    const float* fc_b = (const float*)d_in[6];
    float* out = (float*)d_out;

    // 4096 batches * 8 lanes = 32768 threads; 64-thread blocks -> 512
    // single-wave blocks.
    const int block = 64;
    const int grid  = (4096 * 8) / block;  // 512 blocks
    rnn_os_kernel<<<grid, block, 0, stream>>>(x, W_ih, W_hh, b_ih, b_hh,
                                              fc_w, fc_b, out);
}

// Round 5
// 233.300 us; speedup vs baseline: 1.0118x; 1.0118x over previous
//
#include <hip/hip_runtime.h>

// RNN: h_{t+1} = relu(x_t*W_ih^T + b_ih + b_hh + W_hh·h_t), out = fc(h_T).
// B=4096, T=1000, H=20.
//
// R20: 4 lanes/batch, fold-free. R19b post-mortem: ds_bpermute (LDS pipe,
// ~30+cy) on the serial recurrence = disaster (226us, VALUBusy 18%). Model:
// wall = max(issue/latency limit [rocprof], instr-count power limit
// [harness, ~225 G instr/s]). This design cuts BOTH:
//   lane j of quad owns rows 5j..5j+4, computes full k=0..19 dot -> NO
//   reduction folds, bias counted once, h-gather = 3 quad_perm ROTATIONS
//   (15 v_mov_b32_dpp, VALU pipe, 1 level). Weights rotation-ordered
//   per-lane: slot s multiplies h-set s/5 (rot), element s%5.
//   84 VALU instr/step/wave for 16 batches = 5.25/batch-step (R17: 8.5).
//   Issue 168cy/step -> ~70us @2.4GHz; 21.5M instr total -> ~95us capped.
// 256 single-wave blocks = 1 wave/CU over all 256 CUs.

#define TT 1000

typedef float v2f __attribute__((ext_vector_type(2)));

// one weight column: rows 5j..5j+4 packed (r0,r1),(r2,r3),r4 = 5 VGPRs
struct Col { v2f p01, p23; float v4; };

#define PIN(v)  asm volatile("" : "+v"(v))
__device__ __forceinline__ void pinc(Col& c) {
    PIN(c.p01); PIN(c.p23); PIN(c.v4);
}
__device__ __forceinline__ void keepc(const Col& c) {
    asm volatile("" :: "v"(c.p01), "v"(c.p23), "v"(c.v4));
}

// quad_perm rotate-by-r: lane j reads lane (j+r)&3
#define QP_ROR1 0x39   // [1,2,3,0]
#define QP_ROR2 0x4E   // [2,3,0,1]
#define QP_ROR3 0x93   // [3,0,1,2]

template <int CTRL>
__device__ __forceinline__ float dpp_mov(float v) {
    // old=0 + bound_ctrl -> v_mov_b32_dpp
    return __int_as_float(__builtin_amdgcn_update_dpp(
        0, __float_as_int(v), CTRL, 0xF, 0xF, true));
}

__global__ void
__attribute__((amdgpu_flat_work_group_size(64, 64), amdgpu_waves_per_eu(1, 1)))
rnn_os_kernel(const float* __restrict__ x,
              const float* __restrict__ W_ih,
              const float* __restrict__ W_hh,
              const float* __restrict__ b_ih,
              const float* __restrict__ b_hh,
              const float* __restrict__ fc_w,
              const float* __restrict__ fc_b,
              float* __restrict__ out) {
    const int tid = blockIdx.x * 64 + threadIdx.x;
    const int b   = tid >> 2;     // batch element (4 lanes per batch)
    const int j   = tid & 3;      // lane in quad: owns rows 5j..5j+4

    // --- weight slots, rotation-ordered: slot s multiplies h element
    //     h[5*((j+s/5)&3) + s%5]; weight col index follows the same map.
    Col c0, c1, c2, c3, c4, c5, c6, c7, c8, c9,
        c10, c11, c12, c13, c14, c15, c16, c17, c18, c19;
#define LOADS(ck, s)                                                          \
    { const int own = (j + (s) / 5) & 3;                                      \
      const int ci  = own * 5 + (s) % 5;                                      \
      (ck).p01 = (v2f){ W_hh[(j * 5 + 0) * 20 + ci],                          \
                        W_hh[(j * 5 + 1) * 20 + ci] };                        \
      (ck).p23 = (v2f){ W_hh[(j * 5 + 2) * 20 + ci],                          \
                        W_hh[(j * 5 + 3) * 20 + ci] };                        \
      (ck).v4  =        W_hh[(j * 5 + 4) * 20 + ci]; }
    LOADS(c0, 0)   LOADS(c1, 1)   LOADS(c2, 2)   LOADS(c3, 3)   LOADS(c4, 4)
    LOADS(c5, 5)   LOADS(c6, 6)   LOADS(c7, 7)   LOADS(c8, 8)   LOADS(c9, 9)
    LOADS(c10, 10) LOADS(c11, 11) LOADS(c12, 12) LOADS(c13, 13) LOADS(c14, 14)
    LOADS(c15, 15) LOADS(c16, 16) LOADS(c17, 17) LOADS(c18, 18) LOADS(c19, 19)
#undef LOADS

    // input weights + combined bias for own rows (counted exactly once)
    Col wie, bie;
    {
        const float* pw = W_ih + j * 5;
        const float* p1 = b_ih + j * 5;
        const float* p2 = b_hh + j * 5;
        wie.p01 = (v2f){ pw[0], pw[1] };
        wie.p23 = (v2f){ pw[2], pw[3] };
        wie.v4  = pw[4];
        bie.p01 = (v2f){ p1[0] + p2[0], p1[1] + p2[1] };
        bie.p23 = (v2f){ p1[2] + p2[2], p1[3] + p2[3] };
        bie.v4  = p1[4] + p2[4];
    }

    pinc(c0); pinc(c1); pinc(c2); pinc(c3); pinc(c4);
    pinc(c5); pinc(c6); pinc(c7); pinc(c8); pinc(c9);
    pinc(c10); pinc(c11); pinc(c12); pinc(c13); pinc(c14);
    pinc(c15); pinc(c16); pinc(c17); pinc(c18); pinc(c19);
    pinc(wie); pinc(bie);

    v2f h01 = {0.f, 0.f}, h23 = {0.f, 0.f};
    float h4 = 0.f;

    const float* __restrict__ xb = x + (size_t)b * TT;

    // one timestep: gather 3 rotations, two 10-slot chains, merge, relu
    auto step1 = [&](float xt) {
        // gathers (VALU dpp movs; overlap with own-h MACs below)
        v2f g101, g123; float g14;
        v2f g201, g223; float g24;
        v2f g301, g323; float g34;
        g101.x = dpp_mov<QP_ROR1>(h01.x); g101.y = dpp_mov<QP_ROR1>(h01.y);
        g123.x = dpp_mov<QP_ROR1>(h23.x); g123.y = dpp_mov<QP_ROR1>(h23.y);
        g14    = dpp_mov<QP_ROR1>(h4);
        g201.x = dpp_mov<QP_ROR2>(h01.x); g201.y = dpp_mov<QP_ROR2>(h01.y);
        g223.x = dpp_mov<QP_ROR2>(h23.x); g223.y = dpp_mov<QP_ROR2>(h23.y);
        g24    = dpp_mov<QP_ROR2>(h4);
        g301.x = dpp_mov<QP_ROR3>(h01.x); g301.y = dpp_mov<QP_ROR3>(h01.y);
        g323.x = dpp_mov<QP_ROR3>(h23.x); g323.y = dpp_mov<QP_ROR3>(h23.y);
        g34    = dpp_mov<QP_ROR3>(h4);

#define MACC(A01, A23, a4, hs, hk, ck)                                  \
        A01 = __builtin_elementwise_fma(hs, (ck).p01, A01);             \
        A23 = __builtin_elementwise_fma(hs, (ck).p23, A23);             \
        a4  = __builtin_fmaf(hk, (ck).v4, a4);

        // chain X: init + slots 0..9 (own h, then rot1)
        const v2f xs = {xt, xt};
        v2f  X01 = __builtin_elementwise_fma(xs, wie.p01, bie.p01);
        v2f  X23 = __builtin_elementwise_fma(xs, wie.p23, bie.p23);
        float x4 = __builtin_fmaf(xt, wie.v4, bie.v4);
        MACC(X01, X23, x4, h01.xx, h01.x, c0)
        MACC(X01, X23, x4, h01.yy, h01.y, c1)
        MACC(X01, X23, x4, h23.xx, h23.x, c2)
        MACC(X01, X23, x4, h23.yy, h23.y, c3)
        { const v2f s = {h4, h4};   MACC(X01, X23, x4, s, h4, c4) }
        MACC(X01, X23, x4, g101.xx, g101.x, c5)
        MACC(X01, X23, x4, g101.yy, g101.y, c6)
        MACC(X01, X23, x4, g123.xx, g123.x, c7)
        MACC(X01, X23, x4, g123.yy, g123.y, c8)
        { const v2f s = {g14, g14}; MACC(X01, X23, x4, s, g14, c9) }

        // chain Y: slots 10..19 (rot2, rot3)
        v2f  Y01 = g201.xx * c10.p01;
        v2f  Y23 = g201.xx * c10.p23;
        float y4 = g201.x  * c10.v4;
        MACC(Y01, Y23, y4, g201.yy, g201.y, c11)
        MACC(Y01, Y23, y4, g223.xx, g223.x, c12)
        MACC(Y01, Y23, y4, g223.yy, g223.y, c13)
        { const v2f s = {g24, g24}; MACC(Y01, Y23, y4, s, g24, c14) }
        MACC(Y01, Y23, y4, g301.xx, g301.x, c15)
        MACC(Y01, Y23, y4, g301.yy, g301.y, c16)
        MACC(Y01, Y23, y4, g323.xx, g323.x, c17)
        MACC(Y01, Y23, y4, g323.yy, g323.y, c18)
        { const v2f s = {g34, g34}; MACC(Y01, Y23, y4, s, g34, c19) }
#undef MACC

        // merge + relu
        const v2f z = {0.f, 0.f};
        v2f A01 = X01 + Y01;            // v_pk_add_f32
        v2f A23 = X23 + Y23;
        float a4 = x4 + y4;
        h01 = __builtin_elementwise_max(A01, z);   // v_pk_max_f32
        h23 = __builtin_elementwise_max(A23, z);
        h4  = fmaxf(a4, 0.f);
    };

    // --- 20-step register blocks (5 float4 each), double-buffered.
#define LOAD5(P, off)                                   \
    P##0 = *(const float4*)(xb + (off));                \
    P##1 = *(const float4*)(xb + (off) + 4);            \
    P##2 = *(const float4*)(xb + (off) + 8);            \
    P##3 = *(const float4*)(xb + (off) + 12);           \
    P##4 = *(const float4*)(xb + (off) + 16);

#define RUN4(Q) { step1(Q.x); step1(Q.y); step1(Q.z); step1(Q.w); }
#define RUN20(P) RUN4(P##0) RUN4(P##1) RUN4(P##2) RUN4(P##3) RUN4(P##4)

    float4 A0, A1, A2, A3, A4;
    float4 B0, B1, B2, B3, B4;
    LOAD5(A, 0)    // block 0: steps 0..19
    LOAD5(B, 20)   // block 1: steps 20..39

    // 24 iterations x 40 steps = 960, then blocks 48,49 as the tail.
    // iter it fetches blocks 2it+2, 2it+3; it=23 fetches 48,49 (in-bounds).
    for (int it = 0; it < 24; ++it) {
        const int base = it * 40;
        RUN20(A)                    // steps base .. base+19
        LOAD5(A, base + 40)         // block 2it+2
        RUN20(B)                    // steps base+20 .. base+39
        LOAD5(B, base + 60)         // block 2it+3
    }
    RUN20(A)                        // steps 960..979
    RUN20(B)                        // steps 980..999

#undef RUN20
#undef RUN4
#undef LOAD5

    keepc(c0); keepc(c1); keepc(c2); keepc(c3); keepc(c4);
    keepc(c5); keepc(c6); keepc(c7); keepc(c8); keepc(c9);
    keepc(c10); keepc(c11); keepc(c12); keepc(c13); keepc(c14);
    keepc(c15); keepc(c16); keepc(c17); keepc(c18); keepc(c19);
    keepc(wie); keepc(bie);

    // Final: lane j holds h[5j..5j+4]. Dot with fc_w rows, reduce over quad.
    float dot;
    {
        const float* pf = fc_w + j * 5;
        dot = h01.x * pf[0];
        dot = __builtin_fmaf(h01.y, pf[1], dot);
        dot = __builtin_fmaf(h23.x, pf[2], dot);
        dot = __builtin_fmaf(h23.y, pf[3], dot);
        dot = __builtin_fmaf(h4,    pf[4], dot);
    }
    dot += __shfl_xor(dot, 1, 4);
    dot += __shfl_xor(dot, 2, 4);

    if (j == 0)
        out[b] = dot + fc_b[0];
}

extern "C" void kernel_launch(void* const* d_in, const int* in_sizes, int n_in,
                              void* d_out, int out_size, void* d_ws, size_t ws_size,
                              hipStream_t stream) {
    const float* x    = (const float*)d_in[0];
    const float* W_ih = (const float*)d_in[1];
    const float* W_hh = (const float*)d_in[2];
    const float* b_ih = (const float*)d_in[3];
    const float* b_hh = (const float*)d_in[4];
    const float* fc_w = (const float*)d_in[5];
    const float* fc_b = (const float*)d_in[6];
    float* out = (float*)d_out;

    // 4096 batches * 4 lanes = 16384 threads; 64-thread blocks -> 256
    // single-wave blocks, one per CU.
    const int block = 64;
    const int grid  = (4096 * 4) / block;  // 256 blocks
    rnn_os_kernel<<<grid, block, 0, stream>>>(x, W_ih, W_hh, b_ih, b_hh,
                                              fc_w, fc_b, out);
}